// Round 1
// baseline (64.004 us; speedup 1.0000x reference)
//
#include <hip/hip_runtime.h>
#include <hip/hip_bf16.h>

#define B_SZ 256
#define N_SZ 2000
#define D_SZ 512
#define C_SZ 100
#define BT 8          // batch rows per thread
#define D4 (D_SZ / 4) // 128 float4 chunks per row

// ---------------------------------------------------------------------------
// Prep: label one-hot -> class index per support sample + class counts
// ---------------------------------------------------------------------------
__global__ void prep_kernel(const float* __restrict__ labels,
                            int* __restrict__ idx,
                            float* __restrict__ counts) {
    int n = blockIdx.x * 256 + threadIdx.x;
    if (n < N_SZ) {
        const float* row = labels + (size_t)n * C_SZ;
        int c = 0;
        for (int j = 0; j < C_SZ; ++j) {
            if (row[j] > 0.5f) c = j;
        }
        idx[n] = c;
        atomicAdd(&counts[c], 1.0f);
    }
}

// ---------------------------------------------------------------------------
// Main: each thread owns one support sample n and BT batch rows.
// inputs/w indexed only by uniform (b, d) -> scalar loads (SGPR);
// support row is the per-lane vector stream.
// inner op: acc += w_d * |a_bd - s_nd|  ==  v_sub(s,v) + v_fma(s, |v|, v)
// ---------------------------------------------------------------------------
__global__ __launch_bounds__(256, 1) void score_kernel(
    const float4* __restrict__ inp4,  // [B][D4]
    const float4* __restrict__ sup4,  // [N][D4]
    const float4* __restrict__ w4,    // [D4]
    const float* __restrict__ bias_p, // [1]
    const int* __restrict__ idx,      // [N]
    float* __restrict__ out)          // [B][C] (atomically accumulated)
{
    int n = blockIdx.x * 256 + threadIdx.x;
    int b0 = blockIdx.y * BT;
    bool active = (n < N_SZ);
    int nn = active ? n : 0;

    const float4* __restrict__ srow = sup4 + (size_t)nn * D4;

    float acc[BT];
#pragma unroll
    for (int i = 0; i < BT; ++i) acc[i] = 0.0f;

#pragma unroll 2
    for (int dc = 0; dc < D4; ++dc) {
        float4 sv = srow[dc];
        float4 wv = w4[dc];
#pragma unroll
        for (int i = 0; i < BT; ++i) {
            float4 av = inp4[(size_t)(b0 + i) * D4 + dc];
            acc[i] += wv.x * fabsf(av.x - sv.x);
            acc[i] += wv.y * fabsf(av.y - sv.y);
            acc[i] += wv.z * fabsf(av.z - sv.z);
            acc[i] += wv.w * fabsf(av.w - sv.w);
        }
    }

    if (active) {
        float bias = *bias_p;
        int c = idx[n];
#pragma unroll
        for (int i = 0; i < BT; ++i) {
            float s = 1.0f / (1.0f + __expf(-(acc[i] + bias)));
            atomicAdd(&out[(size_t)(b0 + i) * C_SZ + c], s);
        }
    }
}

// ---------------------------------------------------------------------------
// Epilogue: divide class sums by class counts (divide_no_nan semantics)
// ---------------------------------------------------------------------------
__global__ void div_kernel(float* __restrict__ out,
                           const float* __restrict__ counts) {
    int i = blockIdx.x * 256 + threadIdx.x;
    if (i < B_SZ * C_SZ) {
        float cnt = counts[i % C_SZ];
        float v = out[i];
        out[i] = (cnt != 0.0f) ? v / cnt : 0.0f;
    }
}

extern "C" void kernel_launch(void* const* d_in, const int* in_sizes, int n_in,
                              void* d_out, int out_size, void* d_ws, size_t ws_size,
                              hipStream_t stream) {
    const float* inputs  = (const float*)d_in[0]; // [B, D]
    const float* support = (const float*)d_in[1]; // [N, D]
    const float* labels  = (const float*)d_in[2]; // [N, C]
    const float* w       = (const float*)d_in[3]; // [D]
    const float* bias    = (const float*)d_in[4]; // [1]
    float* out = (float*)d_out;                   // [B, C]

    // Workspace layout: idx[2048] ints, then counts[128] floats
    int*   idx    = (int*)d_ws;
    float* counts = (float*)((char*)d_ws + 2048 * sizeof(int));

    // Zero accumulation targets (harness poisons them to 0xAA)
    hipMemsetAsync(out, 0, (size_t)out_size * sizeof(float), stream);
    hipMemsetAsync(d_ws, 0, 2048 * sizeof(int) + 128 * sizeof(float), stream);

    prep_kernel<<<dim3((N_SZ + 255) / 256), dim3(256), 0, stream>>>(labels, idx, counts);

    dim3 grid((N_SZ + 255) / 256, B_SZ / BT); // 8 x 32 = 256 blocks
    score_kernel<<<grid, dim3(256), 0, stream>>>(
        (const float4*)inputs, (const float4*)support, (const float4*)w,
        bias, idx, out);

    div_kernel<<<dim3((B_SZ * C_SZ + 255) / 256), dim3(256), 0, stream>>>(out, counts);
}

// Round 2
// 57.673 us; speedup vs baseline: 1.1098x; 1.1098x over previous
//
#include <hip/hip_runtime.h>
#include <hip/hip_bf16.h>

#define B_SZ 256
#define N_SZ 2000
#define D_SZ 512
#define C_SZ 100
#define BT 4          // batch rows per thread (round 1: 8 -> occupancy-starved)
#define D4 (D_SZ / 4) // 128 float4 chunks per row

// ---------------------------------------------------------------------------
// Prep: label one-hot -> class index per support sample + class counts
// ---------------------------------------------------------------------------
__global__ void prep_kernel(const float* __restrict__ labels,
                            int* __restrict__ idx,
                            float* __restrict__ counts) {
    int n = blockIdx.x * 256 + threadIdx.x;
    if (n < N_SZ) {
        const float* row = labels + (size_t)n * C_SZ;
        int c = 0;
        for (int j = 0; j < C_SZ; ++j) {
            if (row[j] > 0.5f) c = j;
        }
        idx[n] = c;
        atomicAdd(&counts[c], 1.0f);
    }
}

// ---------------------------------------------------------------------------
// Main: each thread owns one support sample n and BT batch rows.
// inputs/w indexed only by uniform (b, d) -> scalar (SGPR) loads;
// support row is the per-lane vector stream (L1/L2 resident).
// inner op: acc += w_d * |a_bd - s_nd|  ==  v_sub(s,v) + v_fma(s, abs(v), v)
// BT=4, unroll 4: 2 waves/SIMD occupancy, 4 support loads in flight.
// ---------------------------------------------------------------------------
__global__ __launch_bounds__(256, 2) void score_kernel(
    const float4* __restrict__ inp4,  // [B][D4]
    const float4* __restrict__ sup4,  // [N][D4]
    const float4* __restrict__ w4,    // [D4]
    const float* __restrict__ bias_p, // [1]
    const int* __restrict__ idx,      // [N]
    float* __restrict__ out)          // [B][C] (atomically accumulated)
{
    int n = blockIdx.x * 256 + threadIdx.x;
    int b0 = blockIdx.y * BT;
    bool active = (n < N_SZ);
    int nn = active ? n : 0;

    const float4* __restrict__ srow = sup4 + (size_t)nn * D4;

    float acc[BT];
#pragma unroll
    for (int i = 0; i < BT; ++i) acc[i] = 0.0f;

#pragma unroll 4
    for (int dc = 0; dc < D4; ++dc) {
        float4 sv = srow[dc];
        float4 wv = w4[dc];
#pragma unroll
        for (int i = 0; i < BT; ++i) {
            float4 av = inp4[(size_t)(b0 + i) * D4 + dc];
            acc[i] += wv.x * fabsf(av.x - sv.x);
            acc[i] += wv.y * fabsf(av.y - sv.y);
            acc[i] += wv.z * fabsf(av.z - sv.z);
            acc[i] += wv.w * fabsf(av.w - sv.w);
        }
    }

    if (active) {
        float bias = *bias_p;
        int c = idx[n];
#pragma unroll
        for (int i = 0; i < BT; ++i) {
            float s = 1.0f / (1.0f + __expf(-(acc[i] + bias)));
            atomicAdd(&out[(size_t)(b0 + i) * C_SZ + c], s);
        }
    }
}

// ---------------------------------------------------------------------------
// Epilogue: divide class sums by class counts (divide_no_nan semantics)
// ---------------------------------------------------------------------------
__global__ void div_kernel(float* __restrict__ out,
                           const float* __restrict__ counts) {
    int i = blockIdx.x * 256 + threadIdx.x;
    if (i < B_SZ * C_SZ) {
        float cnt = counts[i % C_SZ];
        float v = out[i];
        out[i] = (cnt != 0.0f) ? v / cnt : 0.0f;
    }
}

extern "C" void kernel_launch(void* const* d_in, const int* in_sizes, int n_in,
                              void* d_out, int out_size, void* d_ws, size_t ws_size,
                              hipStream_t stream) {
    const float* inputs  = (const float*)d_in[0]; // [B, D]
    const float* support = (const float*)d_in[1]; // [N, D]
    const float* labels  = (const float*)d_in[2]; // [N, C]
    const float* w       = (const float*)d_in[3]; // [D]
    const float* bias    = (const float*)d_in[4]; // [1]
    float* out = (float*)d_out;                   // [B, C]

    // Workspace layout: idx[2048] ints, then counts[128] floats
    int*   idx    = (int*)d_ws;
    float* counts = (float*)((char*)d_ws + 2048 * sizeof(int));

    // Zero accumulation targets (harness poisons them to 0xAA)
    hipMemsetAsync(out, 0, (size_t)out_size * sizeof(float), stream);
    hipMemsetAsync(d_ws, 0, 2048 * sizeof(int) + 128 * sizeof(float), stream);

    prep_kernel<<<dim3((N_SZ + 255) / 256), dim3(256), 0, stream>>>(labels, idx, counts);

    dim3 grid((N_SZ + 255) / 256, B_SZ / BT); // 8 x 64 = 512 blocks, 2 waves/SIMD
    score_kernel<<<grid, dim3(256), 0, stream>>>(
        (const float4*)inputs, (const float4*)support, (const float4*)w,
        bias, idx, out);

    div_kernel<<<dim3((B_SZ * C_SZ + 255) / 256), dim3(256), 0, stream>>>(out, counts);
}